// Round 5
// baseline (72.112 us; speedup 1.0000x reference)
//
#include <hip/hip_runtime.h>

// SpikeLayer: per-pixel CDF over C=128 channels + S=128 searchsorted lookups.
// B=64, C=128, H=64, W=64, S=128. Output int32 channel indices [B,S,H,W].
//
// R5: overlap the rnd-load latency window with the CDF build. The 16 rnd
// loads are issued at kernel start (they depend on nothing) and pinned in
// registers via empty asm so the compiler cannot sink them past the barriers
// to their use point. Phase 3 then starts with rnd already resident.
// Geometry from R3/R4: 32 pix/block, 8 groups x 16ch, 17.9KB LDS, 8 blk/CU.

#define BB 64
#define CC 128
#define HH 64
#define WW 64
#define SS 128

constexpr int PAD    = 132;          // floats per pixel row (528 B, 16B-aligned)
constexpr int PIX    = 32;           // pixels per block
constexpr int GROUPS = 8;            // thread groups (channel & spike split)
constexpr int KPG    = CC / GROUPS;  // 16 channels per group
constexpr int SPG    = SS / GROUPS;  // 16 spikes per group

__global__ __launch_bounds__(256, 8) void spike_kernel(
    const float* __restrict__ inp,   // [B,C,H,W]
    const float* __restrict__ rnd,   // [B,S,H,W]
    int* __restrict__ out) {         // [B,S,H,W]
  __shared__ float cdf[PIX * PAD];        // 32*132*4 = 16896 B
  __shared__ float gtot[GROUPS * PIX];    // 1024 B

  const int t = threadIdx.x;
  const int p = t & 31;     // pixel within block
  const int g = t >> 5;     // group (0..7)
  const int bid = blockIdx.x;
  const int b    = bid >> 7;          // / (HH*2)
  const int rem  = bid & 127;
  const int h    = rem >> 1;
  const int w0   = (rem & 1) << 5;    // 0 or 32
  const size_t HW = (size_t)HH * WW;
  const size_t pix_off = (size_t)h * WW + w0 + p;

  // ---- issue BOTH read streams up front ----
  const float* rp = rnd + ((size_t)b * SS + g * SPG) * HW + pix_off;
  float rv[SPG];
#pragma unroll
  for (int s = 0; s < SPG; ++s) rv[s] = rp[s * HW];
  // pin: prevent the compiler sinking these loads past the barriers
#pragma unroll
  for (int s = 0; s < SPG; ++s) asm volatile("" : "+v"(rv[s]));

  const float* ip = inp + ((size_t)b * CC + g * KPG) * HW + pix_off;
  float x[KPG];
#pragma unroll
  for (int k = 0; k < KPG; ++k) x[k] = ip[k * HW];

  // ---- phase 1: cumsum in registers ----
  float vals[KPG];
  float run = 0.f;
#pragma unroll
  for (int k = 0; k < KPG; ++k) {
    run += x[k];
    vals[k] = run;
  }
  gtot[g * PIX + p] = run;
  __syncthreads();

  // ---- phase 2: cross-group prefix + vectorized CDF write ----
  float off = 0.f, total = 0.f;
#pragma unroll
  for (int gg = 0; gg < GROUPS; ++gg) {
    const float v = gtot[gg * PIX + p];
    total += v;
    if (gg < g) off += v;
  }

  float4* crow = (float4*)&cdf[p * PAD + g * KPG];
#pragma unroll
  for (int j = 0; j < KPG / 4; ++j) {
    float4 v;
    v.x = vals[4 * j + 0] + off;
    v.y = vals[4 * j + 1] + off;
    v.z = vals[4 * j + 2] + off;
    v.w = vals[4 * j + 3] + off;
    crow[j] = v;
  }
  __syncthreads();

  // ---- phase 3: register-cached top 4 levels, one LDS window per spike ----
  const int base = p * PAD;
  const float c63 = cdf[base + 63];
  const float c31 = cdf[base + 31], c95 = cdf[base + 95];
  const float c15 = cdf[base + 15], c47 = cdf[base + 47];
  const float c79 = cdf[base + 79], c111 = cdf[base + 111];
  const float c7  = cdf[base + 7],  c23 = cdf[base + 23];
  const float c39 = cdf[base + 39], c55 = cdf[base + 55];
  const float c71 = cdf[base + 71], c87 = cdf[base + 87];
  const float c103 = cdf[base + 103], c119 = cdf[base + 119];

  int* op = out + ((size_t)b * SS + g * SPG) * HW + pix_off;

#pragma unroll
  for (int s = 0; s < SPG; ++s) {
    const float r = rv[s] * total;
    const bool bl1 = c63 < r;
    const float v2 = bl1 ? c95 : c31;
    const bool bl2 = v2 < r;
    const float t3a = bl2 ? c47 : c15;
    const float t3b = bl2 ? c111 : c79;
    const float v3 = bl1 ? t3b : t3a;
    const bool bl3 = v3 < r;
    const float t4a = bl3 ? c23 : c7;
    const float t4b = bl3 ? c55 : c39;
    const float t4c = bl3 ? c87 : c71;
    const float t4d = bl3 ? c119 : c103;
    const float u4a = bl2 ? t4b : t4a;
    const float u4b = bl2 ? t4d : t4c;
    const float v4 = bl1 ? u4b : u4a;
    const bool bl4 = v4 < r;
    int idx = (bl1 ? 64 : 0) + (bl2 ? 32 : 0) + (bl3 ? 16 : 0) + (bl4 ? 8 : 0);
    const float4 ca = *(const float4*)&cdf[base + idx];
    const float4 cb = *(const float4*)&cdf[base + idx + 4];
    const int cnt = (ca.x < r) + (ca.y < r) + (ca.z < r) + (ca.w < r)
                  + (cb.x < r) + (cb.y < r) + (cb.z < r);
    __builtin_nontemporal_store(idx + cnt, &op[s * HW]);
  }
}

extern "C" void kernel_launch(void* const* d_in, const int* in_sizes, int n_in,
                              void* d_out, int out_size, void* d_ws, size_t ws_size,
                              hipStream_t stream) {
  const float* inp = (const float*)d_in[0];  // "input"         [B,C,H,W] f32
  const float* rnd = (const float*)d_in[1];  // "random_values" [B,S,H,W] f32
  int* out = (int*)d_out;                    // int32 indices   [B,S,H,W]
  (void)in_sizes; (void)n_in; (void)out_size; (void)d_ws; (void)ws_size;

  spike_kernel<<<dim3(BB * HH * 2), dim3(256), 0, stream>>>(inp, rnd, out);
}

// Round 6
// 68.826 us; speedup vs baseline: 1.0477x; 1.0477x over previous
//
#include <hip/hip_runtime.h>

// SpikeLayer: per-pixel CDF over C=128 channels + S=128 searchsorted lookups.
// B=64, C=128, H=64, W=64, S=128. Output int32 channel indices [B,S,H,W].
//
// R6: (a) merge the two HBM latency windows: issue input loads then rnd loads
// up front, pinned in program order with sched_barrier(0) (a compile-time
// scheduling fence; unlike R5's asm "+v" pin it forces NO waitcnt drain).
// The cumsum waits only on input; rnd flies during cumsum+LDS phases and is
// resident by phase 3. (b) full W-row blocks: 64 px, 512 thr, 8 grp x 16 ch
// -> every input/rnd/out wave-instruction is a 256B contiguous transaction
// (was 128B). LDS 33.9 KB -> 4 blocks x 8 waves = 32 waves/CU unchanged.

#define BB 64
#define CC 128
#define HH 64
#define WW 64
#define SS 128

constexpr int PAD    = 132;          // floats per pixel row (528 B, 16B-aligned)
constexpr int PIX    = 64;           // pixels per block (full W row)
constexpr int GROUPS = 8;            // thread groups (channel & spike split)
constexpr int KPG    = CC / GROUPS;  // 16 channels per group
constexpr int SPG    = SS / GROUPS;  // 16 spikes per group

__global__ __launch_bounds__(512, 8) void spike_kernel(
    const float* __restrict__ inp,   // [B,C,H,W]
    const float* __restrict__ rnd,   // [B,S,H,W]
    int* __restrict__ out) {         // [B,S,H,W]
  __shared__ float cdf[PIX * PAD];        // 64*132*4 = 33792 B
  __shared__ float gtot[GROUPS * PIX];    // 2048 B

  const int t = threadIdx.x;
  const int p = t & 63;     // pixel within row — lane index -> 256B coalesced
  const int g = t >> 6;     // group (0..7), wave-uniform
  const int bid = blockIdx.x;
  const int b = bid >> 6;   // / HH
  const int h = bid & 63;   // % HH
  const size_t HW = (size_t)HH * WW;
  const size_t pix_off = (size_t)h * WW + p;

  // ---- issue both read streams up front: input first, rnd behind it ----
  const float* ip = inp + ((size_t)b * CC + g * KPG) * HW + pix_off;
  float x[KPG];
#pragma unroll
  for (int k = 0; k < KPG; ++k) x[k] = ip[k * HW];

  const float* rp = rnd + ((size_t)b * SS + g * SPG) * HW + pix_off;
  float rv[SPG];
#pragma unroll
  for (int s = 0; s < SPG; ++s) rv[s] = rp[s * HW];

  // compile-time scheduling fence: keep the rnd loads issued HERE (in flight
  // during cumsum + LDS phases); forces no waitcnt, unlike a value pin.
  __builtin_amdgcn_sched_barrier(0);

  // ---- phase 1: cumsum in registers (waits only on the input loads) ----
  float vals[KPG];
  float run = 0.f;
#pragma unroll
  for (int k = 0; k < KPG; ++k) {
    run += x[k];
    vals[k] = run;
  }
  gtot[g * PIX + p] = run;
  __syncthreads();

  // ---- phase 2: cross-group prefix + vectorized CDF write ----
  float off = 0.f, total = 0.f;
#pragma unroll
  for (int gg = 0; gg < GROUPS; ++gg) {
    const float v = gtot[gg * PIX + p];
    total += v;
    if (gg < g) off += v;
  }

  float4* crow = (float4*)&cdf[p * PAD + g * KPG];
#pragma unroll
  for (int j = 0; j < KPG / 4; ++j) {
    float4 v;
    v.x = vals[4 * j + 0] + off;
    v.y = vals[4 * j + 1] + off;
    v.z = vals[4 * j + 2] + off;
    v.w = vals[4 * j + 3] + off;
    crow[j] = v;
  }
  __syncthreads();

  // ---- phase 3: register-cached top 4 levels, one LDS window per spike ----
  const int base = p * PAD;
  const float c63 = cdf[base + 63];
  const float c31 = cdf[base + 31], c95 = cdf[base + 95];
  const float c15 = cdf[base + 15], c47 = cdf[base + 47];
  const float c79 = cdf[base + 79], c111 = cdf[base + 111];
  const float c7  = cdf[base + 7],  c23 = cdf[base + 23];
  const float c39 = cdf[base + 39], c55 = cdf[base + 55];
  const float c71 = cdf[base + 71], c87 = cdf[base + 87];
  const float c103 = cdf[base + 103], c119 = cdf[base + 119];

  int* op = out + ((size_t)b * SS + g * SPG) * HW + pix_off;

#pragma unroll
  for (int s = 0; s < SPG; ++s) {
    const float r = rv[s] * total;
    const bool bl1 = c63 < r;
    const float v2 = bl1 ? c95 : c31;
    const bool bl2 = v2 < r;
    const float t3a = bl2 ? c47 : c15;
    const float t3b = bl2 ? c111 : c79;
    const float v3 = bl1 ? t3b : t3a;
    const bool bl3 = v3 < r;
    const float t4a = bl3 ? c23 : c7;
    const float t4b = bl3 ? c55 : c39;
    const float t4c = bl3 ? c87 : c71;
    const float t4d = bl3 ? c119 : c103;
    const float u4a = bl2 ? t4b : t4a;
    const float u4b = bl2 ? t4d : t4c;
    const float v4 = bl1 ? u4b : u4a;
    const bool bl4 = v4 < r;
    int idx = (bl1 ? 64 : 0) + (bl2 ? 32 : 0) + (bl3 ? 16 : 0) + (bl4 ? 8 : 0);
    const float4 ca = *(const float4*)&cdf[base + idx];
    const float4 cb = *(const float4*)&cdf[base + idx + 4];
    const int cnt = (ca.x < r) + (ca.y < r) + (ca.z < r) + (ca.w < r)
                  + (cb.x < r) + (cb.y < r) + (cb.z < r);
    __builtin_nontemporal_store(idx + cnt, &op[s * HW]);
  }
}

extern "C" void kernel_launch(void* const* d_in, const int* in_sizes, int n_in,
                              void* d_out, int out_size, void* d_ws, size_t ws_size,
                              hipStream_t stream) {
  const float* inp = (const float*)d_in[0];  // "input"         [B,C,H,W] f32
  const float* rnd = (const float*)d_in[1];  // "random_values" [B,S,H,W] f32
  int* out = (int*)d_out;                    // int32 indices   [B,S,H,W]
  (void)in_sizes; (void)n_in; (void)out_size; (void)d_ws; (void)ws_size;

  spike_kernel<<<dim3(BB * HH), dim3(512), 0, stream>>>(inp, rnd, out);
}

// Round 7
// 67.671 us; speedup vs baseline: 1.0656x; 1.0171x over previous
//
#include <hip/hip_runtime.h>

// SpikeLayer: per-pixel CDF over C=128 channels + S=128 searchsorted lookups.
// B=64, C=128, H=64, W=64, S=128. Output int32 channel indices [B,S,H,W].
//
// R7: (a) rnd-load residency, done right this time: issue x loads then rv
// loads up front; pin rv with empty asm AFTER the cumsum and right BEFORE
// __syncthreads — the forced vmcnt wait coincides with the barrier's own
// vmcnt(0) drain (zero cost), but the compiler can no longer sink the rv
// loads to phase 3. One merged HBM latency window per wave instead of two.
// (b) granule XOR-swizzle of the per-pixel CDF row: dword d lives at
// p*132 + (d ^ (p&56)). Kills the ds_read_b128 window bank conflicts
// (12.8M cy -> ~free 2-way) while keeping 16B alignment and window
// contiguity. Geometry: 64 px/block, 512 thr, 8 grp x 16 ch, 35.8KB LDS,
// 4 blk x 8 waves = 32 waves/CU.

#define BB 64
#define CC 128
#define HH 64
#define WW 64
#define SS 128

constexpr int PAD    = 132;          // floats per pixel row (528 B, 16B-aligned)
constexpr int PIX    = 64;           // pixels per block (full W row)
constexpr int GROUPS = 8;            // thread groups (channel & spike split)
constexpr int KPG    = CC / GROUPS;  // 16 channels per group
constexpr int SPG    = SS / GROUPS;  // 16 spikes per group

__global__ __launch_bounds__(512, 8) void spike_kernel(
    const float* __restrict__ inp,   // [B,C,H,W]
    const float* __restrict__ rnd,   // [B,S,H,W]
    int* __restrict__ out) {         // [B,S,H,W]
  __shared__ float cdf[PIX * PAD];        // 64*132*4 = 33792 B
  __shared__ float gtot[GROUPS * PIX];    // 2048 B

  const int t = threadIdx.x;
  const int p = t & 63;     // pixel within row — lane index -> 256B coalesced
  const int g = t >> 6;     // group (0..7), wave-uniform
  const int bid = blockIdx.x;
  const int b = bid >> 6;   // / HH
  const int h = bid & 63;   // % HH
  const size_t HW = (size_t)HH * WW;
  const size_t pix_off = (size_t)h * WW + p;
  const int swz = p & 56;             // ((p>>3)&7)<<3 — granule swizzle bits
  const int rowbase = p * PAD;

  // ---- issue both read streams up front: input first, rnd behind it ----
  const float* ip = inp + ((size_t)b * CC + g * KPG) * HW + pix_off;
  float x[KPG];
#pragma unroll
  for (int k = 0; k < KPG; ++k) x[k] = ip[k * HW];

  const float* rp = rnd + ((size_t)b * SS + g * SPG) * HW + pix_off;
  float rv[SPG];
#pragma unroll
  for (int s = 0; s < SPG; ++s) rv[s] = rp[s * HW];
  __builtin_amdgcn_sched_barrier(0);  // keep the issue point here

  // ---- phase 1: cumsum in registers (waits only on the x loads) ----
  float vals[KPG];
  float run = 0.f;
#pragma unroll
  for (int k = 0; k < KPG; ++k) {
    run += x[k];
    vals[k] = run;
  }
  gtot[g * PIX + p] = run;

  // pin rv values live HERE: the implied vmcnt wait merges with the
  // barrier's own vmcnt(0) drain, so this is free — but it forbids the
  // compiler from sinking the rv loads below the barriers.
#pragma unroll
  for (int s = 0; s < SPG; ++s) asm volatile("" : "+v"(rv[s]));
  __syncthreads();

  // ---- phase 2: cross-group prefix + swizzled vectorized CDF write ----
  float off = 0.f, total = 0.f;
#pragma unroll
  for (int gg = 0; gg < GROUPS; ++gg) {
    const float v = gtot[gg * PIX + p];
    total += v;
    if (gg < g) off += v;
  }

#pragma unroll
  for (int j = 0; j < KPG / 4; ++j) {
    const int d = g * KPG + 4 * j;            // dword index, multiple of 4
    float4 v;
    v.x = vals[4 * j + 0] + off;
    v.y = vals[4 * j + 1] + off;
    v.z = vals[4 * j + 2] + off;
    v.w = vals[4 * j + 3] + off;
    *(float4*)&cdf[rowbase + (d ^ swz)] = v;  // swizzle keeps 16B alignment
  }
  __syncthreads();

  // ---- phase 3: register-cached top 4 levels, one LDS window per spike ----
#define LDC(d) cdf[rowbase + ((d) ^ swz)]
  const float c63 = LDC(63);
  const float c31 = LDC(31), c95 = LDC(95);
  const float c15 = LDC(15), c47 = LDC(47);
  const float c79 = LDC(79), c111 = LDC(111);
  const float c7  = LDC(7),  c23 = LDC(23);
  const float c39 = LDC(39), c55 = LDC(55);
  const float c71 = LDC(71), c87 = LDC(87);
  const float c103 = LDC(103), c119 = LDC(119);
#undef LDC

  int* op = out + ((size_t)b * SS + g * SPG) * HW + pix_off;

#pragma unroll
  for (int s = 0; s < SPG; ++s) {
    const float r = rv[s] * total;
    const bool bl1 = c63 < r;
    const float v2 = bl1 ? c95 : c31;
    const bool bl2 = v2 < r;
    const float t3a = bl2 ? c47 : c15;
    const float t3b = bl2 ? c111 : c79;
    const float v3 = bl1 ? t3b : t3a;
    const bool bl3 = v3 < r;
    const float t4a = bl3 ? c23 : c7;
    const float t4b = bl3 ? c55 : c39;
    const float t4c = bl3 ? c87 : c71;
    const float t4d = bl3 ? c119 : c103;
    const float u4a = bl2 ? t4b : t4a;
    const float u4b = bl2 ? t4d : t4c;
    const float v4 = bl1 ? u4b : u4a;
    const bool bl4 = v4 < r;
    const int idx = (bl1 ? 64 : 0) + (bl2 ? 32 : 0) + (bl3 ? 16 : 0) + (bl4 ? 8 : 0);
    const int wd = idx ^ swz;                  // multiple of 8 -> 16B aligned
    const float4 ca = *(const float4*)&cdf[rowbase + wd];
    const float4 cb = *(const float4*)&cdf[rowbase + wd + 4];
    const int cnt = (ca.x < r) + (ca.y < r) + (ca.z < r) + (ca.w < r)
                  + (cb.x < r) + (cb.y < r) + (cb.z < r);
    __builtin_nontemporal_store(idx + cnt, &op[s * HW]);
  }
}

extern "C" void kernel_launch(void* const* d_in, const int* in_sizes, int n_in,
                              void* d_out, int out_size, void* d_ws, size_t ws_size,
                              hipStream_t stream) {
  const float* inp = (const float*)d_in[0];  // "input"         [B,C,H,W] f32
  const float* rnd = (const float*)d_in[1];  // "random_values" [B,S,H,W] f32
  int* out = (int*)d_out;                    // int32 indices   [B,S,H,W]
  (void)in_sizes; (void)n_in; (void)out_size; (void)d_ws; (void)ws_size;

  spike_kernel<<<dim3(BB * HH), dim3(512), 0, stream>>>(inp, rnd, out);
}